// Round 6
// baseline (246.209 us; speedup 1.0000x reference)
//
#include <hip/hip_runtime.h>

#define OUT_DIM 4096
#define DPC     16
#define NCOL    65536    // OUT_DIM * DPC
#define BATCH   512
#define NCHUNK  4096     // BATCH * 8 chunks of 512 windows
#define NBLK    1024     // persistent grid: 4 blocks/CU * 256 CU
#define ITERS   (NCHUNK / NBLK)   // 4

typedef float nvec4 __attribute__((ext_vector_type(4)));   // clang-native f32x4

// Kernel 1: bf[p] = exp((1/16 - duty[p]) * bs), double-prec exp rounded to fp32
__global__ void boost_table_kernel(const float* __restrict__ duty,
                                   const float* __restrict__ bs_ptr,
                                   float* __restrict__ bf) {
    int p = blockIdx.x * blockDim.x + threadIdx.x;
    if (p < NCOL) {
        float t = (0.0625f - duty[p]) * bs_ptr[0];
        bf[p] = (float)exp((double)t);
    }
}

// LDS-only barrier: all cross-wave data in this kernel moves through LDS, so
// only lgkmcnt must drain. Crucially this does NOT emit s_waitcnt vmcnt(0)
// (which __syncthreads does), so prefetch loads and NT stores stay in flight
// across barriers -> the VMEM queue never drains, MLP stays high.
__device__ __forceinline__ void lds_barrier() {
    asm volatile("s_waitcnt lgkmcnt(0)" ::: "memory");
    __builtin_amdgcn_s_barrier();
}

// Kernel 2: persistent pipelined streaming. Chunk = (row r, eighth h): 512
// windows; input span [7680h, 7680h+7696) staged as 8192 floats (32 KiB),
// out span [8192h, +8192).
//   per iteration: P1 boost(prefetched regs)->ds_write | barrier |
//   P2 issue xo loads (L2-hot), issue NEXT chunk x/bf loads, argmax->sjb |
//   barrier | P3 masked NT stores.
// vmcnt is in-order: xo issued BEFORE prefetch so P3's xo wait doesn't wait
// on HBM prefetch; stores issued last so nothing waits on them.
// Chunk stride 1024 == 0 mod 8 -> each XCD serves one h forever: its 30 KiB
// bf span is L2-resident.
__global__ __launch_bounds__(256, 4) void dkw_kernel(const float* __restrict__ x,
                                                     const float* __restrict__ bf,
                                                     float* __restrict__ out) {
    __shared__ float sb[8192];             // boosted input span, 32 KiB
    __shared__ unsigned char sjb[512];     // winner j per window

    const int tid = threadIdx.x;           // 0..255 (4 waves)
    int c = blockIdx.x;                    // chunk id; r = c>>3, h = c&7

    // prologue: issue x/bf loads for first chunk
    float4 xn[8], bn[8];
    {
        const int r = c >> 3, h = c & 7;
        const float4* __restrict__ xg = (const float4*)(x + (r << 16) + h * 7680);
        const float4* __restrict__ bg = (const float4*)(bf + h * 7680);
        #pragma unroll
        for (int k = 0; k < 8; ++k) {
            xn[k] = xg[tid + (k << 8)];
            bn[k] = bg[tid + (k << 8)];
        }
    }

    float4* sb4 = (float4*)sb;
    #pragma unroll 1
    for (int it = 0; it < ITERS; ++it) {
        const int r = c >> 3, h = c & 7;

        // ---- P1: boost prefetched regs -> LDS (conflict-free b128) ----
        #pragma unroll
        for (int k = 0; k < 8; ++k) {
            float4 a = xn[k], bq = bn[k];
            a.x *= bq.x; a.y *= bq.y; a.z *= bq.z; a.w *= bq.w;
            sb4[tid + (k << 8)] = a;
        }
        lds_barrier();   // staged span visible; argmax reads of prev iter done

        // ---- P2a: xo loads FIRST (L2-hot out-span, consumed in P3) ----
        const float4* __restrict__ xo_g = (const float4*)(x + (r << 16) + (h << 13));
        float4 xo[8];
        #pragma unroll
        for (int k = 0; k < 8; ++k)
            xo[k] = xo_g[tid + (k << 8)];

        // ---- P2b: prefetch NEXT chunk x/bf (consumed next iteration) ----
        const int cn = c + NBLK;
        if (cn < NCHUNK) {
            const int rn = cn >> 3, hn = cn & 7;
            const float4* __restrict__ xg = (const float4*)(x + (rn << 16) + hn * 7680);
            const float4* __restrict__ bg = (const float4*)(bf + hn * 7680);
            #pragma unroll
            for (int k = 0; k < 8; ++k) {
                xn[k] = xg[tid + (k << 8)];
                bn[k] = bg[tid + (k << 8)];
            }
        }

        // ---- P2c: argmax, windows w = tid, tid+256 (stride-15: 2-way = free) ----
        #pragma unroll
        for (int m = 0; m < 2; ++m) {
            const int w = tid + (m << 8);
            const float* __restrict__ p = sb + w * 15;
            float best = p[0];
            int   bj   = 0;
            #pragma unroll
            for (int kk = 1; kk < DPC; ++kk) {
                float v = p[kk];
                if (v > best) { best = v; bj = kk; }   // strict >: first max wins
            }
            sjb[w] = (unsigned char)bj;
        }
        lds_barrier();   // sjb visible; prev-iter sjb reads already done pre-P1

        // ---- P3: masked coalesced NT stores ----
        float4* __restrict__ og4 = (float4*)(out + (r << 16) + (h << 13));
        #pragma unroll
        for (int k = 0; k < 8; ++k) {
            const int o4 = tid + (k << 8);
            const int jm = (int)sjb[o4 >> 2];          // 4-lane broadcast: free
            const int j0 = (o4 & 3) << 2;
            const float4 v = xo[k];
            float4 o;
            o.x = (j0     == jm) ? v.x : 0.0f;
            o.y = (j0 + 1 == jm) ? v.y : 0.0f;
            o.z = (j0 + 2 == jm) ? v.z : 0.0f;
            o.w = (j0 + 3 == jm) ? v.w : 0.0f;
            __builtin_nontemporal_store(*(const nvec4*)&o, (nvec4*)&og4[o4]);
        }
        c = cn;
    }
}

extern "C" void kernel_launch(void* const* d_in, const int* in_sizes, int n_in,
                              void* d_out, int out_size, void* d_ws, size_t ws_size,
                              hipStream_t stream) {
    const float* x    = (const float*)d_in[0];
    const float* duty = (const float*)d_in[1];
    const float* bs   = (const float*)d_in[2];
    float* out = (float*)d_out;
    float* bf  = (float*)d_ws;   // 65536 floats = 256 KiB scratch

    hipLaunchKernelGGL(boost_table_kernel, dim3(NCOL / 256), dim3(256), 0, stream,
                       duty, bs, bf);
    hipLaunchKernelGGL(dkw_kernel, dim3(NBLK), dim3(256), 0, stream,
                       x, bf, out);
}

// Round 7
// 241.979 us; speedup vs baseline: 1.0175x; 1.0175x over previous
//
#include <hip/hip_runtime.h>

#define OUT_DIM 4096
#define DPC     16
#define NCOL    65536    // OUT_DIM * DPC
#define BATCH   512
#define NCHUNK  4096     // 512-window chunks: 8 per row, 512 rows

typedef float nvec4 __attribute__((ext_vector_type(4)));   // clang-native f32x4

// Kernel 1: bf[p] = exp((1/16 - duty[p]) * bs), double-prec exp rounded to fp32
__global__ void boost_table_kernel(const float* __restrict__ duty,
                                   const float* __restrict__ bs_ptr,
                                   float* __restrict__ bf) {
    int p = blockIdx.x * blockDim.x + threadIdx.x;
    if (p < NCOL) {
        float t = (0.0625f - duty[p]) * bs_ptr[0];
        bf[p] = (float)exp((double)t);
    }
}

// LDS-only barrier: no vmcnt drain, loads/NT-stores stay in flight across it.
__device__ __forceinline__ void lds_barrier() {
    asm volatile("s_waitcnt lgkmcnt(0)" ::: "memory");
    __builtin_amdgcn_s_barrier();
}

// Kernel 2: single-read + free-flow. Block = (row r, eighth h): 512 windows.
//   union span (raw x), row-local f4 [1920h, 2048h+2048), U = 2048+128h f4
//   (covers input span [1920h, +1924) AND out span [2048h, +2048)).
// P1: union -> xn[6] regs (guard i<U); boosted = xn*bf -> LDS (i<1924 only).
//     Raw x never goes to LDS; bf is transient (L2-hot table).
// P2: stride-15 argmax from LDS (bank: 15l mod 32, 2-way = free) -> sjb byte.
// P3: ROTATION stores: out-f4 j == union-f4 i = j+128h, already in thread
//     (i%512)'s xn[i/512] -> mask by sjb, coalesced NT store. No re-read.
// Lean VGPR (~xn 24 + temps) -> launch_bounds(512,8) caps 64 -> 4 blocks/CU
// = 32 waves/CU; blocks retire independently so per-CU phases stay mixed
// (the R2 free-flow regime) instead of lockstep.
__global__ __launch_bounds__(512, 8) void dkw_kernel(const float* __restrict__ x,
                                                     const float* __restrict__ bf,
                                                     float* __restrict__ out) {
    __shared__ float sb[7696];             // boosted input span, 30.1 KiB
    __shared__ unsigned char sjb[512];     // winner j per window

    const int tid = threadIdx.x;           // 0..511 (8 waves)
    const int r   = blockIdx.x >> 3;       // row
    const int h   = blockIdx.x & 7;        // eighth within row
    const int U   = 2048 + (h << 7);       // union length in f4
    const int off = h << 7;                // out-span offset within union (f4)

    const float4* __restrict__ xg4 = (const float4*)x + (r << 14) + 1920 * h;
    const float4* __restrict__ bg4 = (const float4*)bf + 1920 * h;
    float4* sb4 = (float4*)sb;

    // ---- P1: raw union -> regs; boosted input span -> LDS ----
    float4 xn[6];                          // <= 5.75 f4/thread (h=7)
    #pragma unroll
    for (int k = 0; k < 6; ++k) {
        const int i = tid + (k << 9);
        if (i < U) xn[k] = xg4[i];         // divergent only at boundary k
    }
    #pragma unroll
    for (int k = 0; k < 4; ++k) {
        const int i = tid + (k << 9);
        if (i < 1924) {                    // input span = 1924 f4 (7696 floats)
            float4 a = xn[k];              // i<1924 < U: always loaded
            float4 q = bg4[i];             // L2-resident table, transient regs
            a.x *= q.x; a.y *= q.y; a.z *= q.z; a.w *= q.w;
            sb4[i] = a;                    // conflict-free ds_write_b128
        }
    }
    lds_barrier();

    // ---- P2: argmax, window w = tid (stride-15 floats, 2-way bank = free) ----
    {
        const float* __restrict__ p = sb + tid * 15;
        float best = p[0];
        int   bj   = 0;
        #pragma unroll
        for (int kk = 1; kk < DPC; ++kk) {
            float v = p[kk];
            if (v > best) { best = v; bj = kk; }   // strict >: first max wins
        }
        sjb[tid] = (unsigned char)bj;
    }
    lds_barrier();

    // ---- P3: rotated-register masked NT stores (coalesced) ----
    float4* __restrict__ og4 = (float4*)out + (r << 14) + (h << 11);
    #pragma unroll
    for (int k = 0; k < 6; ++k) {
        const int i = tid + (k << 9);
        if (i >= off && i < U) {           // out-f4 j = i - off in [0,2048)
            const int j  = i - off;
            const int jm = (int)sjb[j >> 2];       // 4-lane broadcast: free
            const int j0 = (j & 3) << 2;
            const float4 v = xn[k];
            float4 o;
            o.x = (j0     == jm) ? v.x : 0.0f;
            o.y = (j0 + 1 == jm) ? v.y : 0.0f;
            o.z = (j0 + 2 == jm) ? v.z : 0.0f;
            o.w = (j0 + 3 == jm) ? v.w : 0.0f;
            __builtin_nontemporal_store(*(const nvec4*)&o, (nvec4*)&og4[j]);
        }
    }
}

extern "C" void kernel_launch(void* const* d_in, const int* in_sizes, int n_in,
                              void* d_out, int out_size, void* d_ws, size_t ws_size,
                              hipStream_t stream) {
    const float* x    = (const float*)d_in[0];
    const float* duty = (const float*)d_in[1];
    const float* bs   = (const float*)d_in[2];
    float* out = (float*)d_out;
    float* bf  = (float*)d_ws;   // 65536 floats = 256 KiB scratch

    hipLaunchKernelGGL(boost_table_kernel, dim3(NCOL / 256), dim3(256), 0, stream,
                       duty, bs, bf);
    hipLaunchKernelGGL(dkw_kernel, dim3(NCHUNK), dim3(512), 0, stream,
                       x, bf, out);
}